// Round 4
// baseline (686.550 us; speedup 1.0000x reference)
//
#include <hip/hip_runtime.h>
#include <hip/hip_bf16.h>

// Shapes
#define M_CELLS 4096
#define N_GENES 4000
#define KP      4032   // 63 * 64, zero-padded K
#define NKT     63     // K tiles of 64
#define N_OUT   12288  // 64 patches * 192 embed
#define EMB     192
#define NPATCH  64

#define BM 256
#define BN 256
#define BK 64
#define BTILE (BN * BK)   // 16384 elems per B K-tile

typedef __attribute__((ext_vector_type(8))) short bf16x8_t;
typedef __attribute__((ext_vector_type(8))) unsigned short u16x8_t;
typedef __attribute__((ext_vector_type(4))) float f32x4_t;

__device__ __forceinline__ unsigned short f2bf(float f) {
  __hip_bfloat16 h = __float2bfloat16(f);
  return *reinterpret_cast<unsigned short*>(&h);
}

__device__ __forceinline__ void gll16(const unsigned short* g, unsigned short* l) {
  __builtin_amdgcn_global_load_lds(
      (const __attribute__((address_space(1))) void*)g,
      (__attribute__((address_space(3))) void*)l, 16, 0, 0);
}

// ---------------- fused prep: blocks [0,1024) do prepA, [1024,4048) do prepB ----------------
// prepA: x fp32[4096x4000] -> bf16 A'[4096x4032] (zero-pad K)
// prepB: W*mask -> bf16 Bt tiled [nt][kt][c=256][k=64] via LDS re-order (512B output runs)
__global__ __launch_bounds__(256) void prep_fused(const float* __restrict__ x,
                                                  const float* __restrict__ mask,
                                                  const float* __restrict__ W,
                                                  unsigned short* __restrict__ A,
                                                  unsigned short* __restrict__ Bt) {
  __shared__ unsigned short sT[256 * 72];  // used by prepB part only
  const int t = threadIdx.x;
  if (blockIdx.x < 1024) {
    const int NG = M_CELLS * (KP / 8);
    for (int g = blockIdx.x * 256 + t; g < NG; g += 1024 * 256) {
      int row = g / (KP / 8);
      int kc  = g - row * (KP / 8);
      int k   = kc * 8;
      u16x8_t v;
      if (k < N_GENES) {
        float4 f0 = *reinterpret_cast<const float4*>(x + (size_t)row * N_GENES + k);
        float4 f1 = *reinterpret_cast<const float4*>(x + (size_t)row * N_GENES + k + 4);
        v[0] = f2bf(f0.x); v[1] = f2bf(f0.y); v[2] = f2bf(f0.z); v[3] = f2bf(f0.w);
        v[4] = f2bf(f1.x); v[5] = f2bf(f1.y); v[6] = f2bf(f1.z); v[7] = f2bf(f1.w);
      } else {
        v = (u16x8_t)0;
      }
      *reinterpret_cast<u16x8_t*>(A + (size_t)row * KP + k) = v;
    }
  } else {
    const int idx = blockIdx.x - 1024;
    const int jb  = idx % 48;      // 0..47
    const int kt  = idx / 48;      // 0..62
    const int j   = jb * 256 + t;
    const int pw  = j / EMB;
#pragma unroll
    for (int ch = 0; ch < 8; ++ch) {
      u16x8_t v;
#pragma unroll
      for (int u = 0; u < 8; ++u) {
        int kg = kt * 64 + ch * 8 + u;
        float val = 0.f;
        if (kg < N_GENES) val = W[(size_t)kg * N_OUT + j] * mask[kg * NPATCH + pw];
        v[u] = f2bf(val);
      }
      *reinterpret_cast<u16x8_t*>(&sT[t * 72 + ch * 8]) = v;
    }
    __syncthreads();
#pragma unroll
    for (int it = 0; it < 8; ++it) {
      int f  = it * 256 + t;
      int p  = f >> 5, u = f & 31;
      int el = u >> 3, k0 = (u & 7) * 8;
      u16x8_t v = *reinterpret_cast<const u16x8_t*>(&sT[(el * 64 + p) * 72 + k0]);
      int jp0 = p * EMB + jb * 4;
      int nt  = jp0 >> 8, c = jp0 & 255;
      *reinterpret_cast<u16x8_t*>(&Bt[(size_t)(nt * NKT + kt) * BTILE + (size_t)c * 64 + u * 8]) = v;
    }
  }
}

// ---------------- main GEMM: 256x256, BK=64, 8-window schedule, reg-pipelined ds_reads -------
// LDS slots: E0=buf0ks0, E1=buf0ks1, O0=buf1ks0, O1=buf1ks1 (each 16KB A + 16KB B).
// Window w: issue ds_reads for phase w+1; counted lgkm waits only for phase w's regs;
// MFMA_w overlaps the new reads' drain. vmcnt(6) at odd-window closes guards slot 3 back.
#define ABASE(buf, ks) (((buf) * 2 + (ks)) * 8192)
#define BBASE(buf, ks) (32768 + ((buf) * 2 + (ks)) * 8192)

__global__ __launch_bounds__(512, 2) void gemm_bf16(const unsigned short* __restrict__ A,
                                                    const unsigned short* __restrict__ Bt,
                                                    const float* __restrict__ bias,
                                                    float* __restrict__ out) {
  __shared__ unsigned short lds[65536];  // 128 KiB

  const int tid  = threadIdx.x;
  const int lane = tid & 63;
  const int wid  = tid >> 6;
  const int wm   = wid >> 2;   // 0..1
  const int wn   = wid & 3;    // 0..3
  const int lr   = lane & 15;
  const int hi   = lane >> 4;  // 0..3
  const int swz  = (lr >> 1) & 3;

  // XCD-chunked mapping: grid 768 = 8 XCDs x (16 mt x 6 nt_local).
  const int bid = blockIdx.x;
  const int xcd = bid & 7;
  const int l   = bid >> 3;
  const int mt  = l & 15;
  const int nt  = xcd * 6 + (l >> 4);
  const int m0  = mt * BM;
  const int n0  = nt * BN;

  // fragment LDS element offsets (within a [256][32] chunk), swizzle slot^((row>>1)&3)
  const int aoff = (wm * 128 + lr) * 32 + ((hi ^ swz) << 3);
  const int boff = (wn * 64 + lr) * 32 + ((hi ^ swz) << 3);

  // staging source base pointers (per-thread); LDS dest linear tid*16B (+4096 elems)
  const int srow = tid >> 2;
  const int ssl  = ((tid & 3) ^ ((tid >> 3) & 3)) << 3;  // inverse-swizzled 16B slot
  const unsigned short* aS0 = A + (size_t)(m0 + srow) * KP + ssl;
  const unsigned short* aS1 = aS0 + (size_t)128 * KP;
  const unsigned short* bS0 = Bt + (size_t)nt * NKT * BTILE + (size_t)srow * 64 + ssl;
  const unsigned short* bS1 = bS0 + 8192;

#define STAGE_A(kt, kh, buf) { \
    gll16(aS0 + (kt) * 64 + (kh) * 32, &lds[ABASE(buf, kh) + tid * 8]); \
    gll16(aS1 + (kt) * 64 + (kh) * 32, &lds[ABASE(buf, kh) + 4096 + tid * 8]); }
#define STAGE_B(kt, kh, buf) { \
    gll16(bS0 + (size_t)(kt) * BTILE + (kh) * 32, &lds[BBASE(buf, kh) + tid * 8]); \
    gll16(bS1 + (size_t)(kt) * BTILE + (kh) * 32, &lds[BBASE(buf, kh) + 4096 + tid * 8]); }

#define RD_AF(bk, buf, ks) \
    _Pragma("unroll") for (int m_ = 0; m_ < 8; ++m_) \
      af[bk][m_] = *reinterpret_cast<const bf16x8_t*>(&lds[ABASE(buf, ks) + aoff + m_ * 512]);
#define RD_B(bk, buf, ks, nh) { \
    bfr[bk][0] = *reinterpret_cast<const bf16x8_t*>(&lds[BBASE(buf, ks) + boff + (nh) * 1024]); \
    bfr[bk][1] = *reinterpret_cast<const bf16x8_t*>(&lds[BBASE(buf, ks) + boff + (nh) * 1024 + 512]); }

#define MM(abk, bbk, nh) \
    __builtin_amdgcn_s_setprio(1); \
    _Pragma("unroll") for (int m_ = 0; m_ < 8; ++m_) { \
      acc[m_][(nh)*2+0] = __builtin_amdgcn_mfma_f32_16x16x32_bf16(af[abk][m_], bfr[bbk][0], acc[m_][(nh)*2+0], 0, 0, 0); \
      acc[m_][(nh)*2+1] = __builtin_amdgcn_mfma_f32_16x16x32_bf16(af[abk][m_], bfr[bbk][1], acc[m_][(nh)*2+1], 0, 0, 0); } \
    __builtin_amdgcn_s_setprio(0);

#define LGKM(n) asm volatile("s_waitcnt lgkmcnt(" #n ")" ::: "memory"); \
    __builtin_amdgcn_sched_barrier(0);
#define VMC(n)  asm volatile("s_waitcnt vmcnt(" #n ")" ::: "memory");
#define BARC()  __builtin_amdgcn_s_barrier(); __builtin_amdgcn_sched_barrier(0);

  f32x4_t acc[8][4] = {};
  bf16x8_t af[2][8], bfr[2][2];

  // Prologue: stage E0, E1, O0 (12 loads); vmcnt(8) -> E0 done; issue P1 reads.
  STAGE_A(0, 0, 0); STAGE_B(0, 0, 0);
  STAGE_A(0, 1, 0); STAGE_B(0, 1, 0);
  STAGE_A(1, 0, 1); STAGE_B(1, 0, 1);
  VMC(8);
  BARC();
  RD_AF(0, 0, 0); RD_B(0, 0, 0, 0);   // P1 regs (E0)

  for (int i = 0; i < 31; ++i) {
    const int tb = 2 * i + 1, tc = 2 * i + 2;
    const int td = (tb + 2 <= 62) ? tb + 2 : 62;  // clamped dummy stage on last iter

    // W1: MFMA P1(E0,ks0,n01; af0,bf0); reads P2 -> bf1; stage A(tb,k1)->O1; guard E1
    RD_B(1, 0, 0, 1);
    STAGE_A(tb, 1, 1);
    LGKM(2); MM(0, 0, 0);
    VMC(6); BARC();
    // W2: MFMA P2(E0,ks0,n23; af0,bf1); reads P3 -> af1,bf0 (E1); stage B(tb,k1)->O1
    RD_AF(1, 0, 1); RD_B(0, 0, 1, 0);
    STAGE_B(tb, 1, 1);
    LGKM(10); MM(0, 1, 1);
    BARC();
    // W3: MFMA P3(E1,n01; af1,bf0); reads P4 -> bf1; stage A(tc,k0)->E0'; guard O0
    RD_B(1, 0, 1, 1);
    STAGE_A(tc, 0, 0);
    LGKM(2); MM(1, 0, 0);
    VMC(6); BARC();
    // W4: MFMA P4(E1,n23; af1,bf1); reads P5 -> af0,bf0 (O0); stage B(tc,k0)->E0'
    RD_AF(0, 1, 0); RD_B(0, 1, 0, 0);
    STAGE_B(tc, 0, 0);
    LGKM(10); MM(1, 1, 1);
    BARC();
    // W5: MFMA P5(O0,n01; af0,bf0); reads P6 -> bf1; stage A(tc,k1)->E1'; guard O1
    RD_B(1, 1, 0, 1);
    STAGE_A(tc, 1, 0);
    LGKM(2); MM(0, 0, 0);
    VMC(6); BARC();
    // W6: MFMA P6(O0,n23; af0,bf1); reads P7 -> af1,bf0 (O1); stage B(tc,k1)->E1'
    RD_AF(1, 1, 1); RD_B(0, 1, 1, 0);
    STAGE_B(tc, 1, 0);
    LGKM(10); MM(0, 1, 1);
    BARC();
    // W7: MFMA P7(O1,n01; af1,bf0); reads P8 -> bf1; stage A(td,k0)->O0'; guard E0'
    RD_B(1, 1, 1, 1);
    STAGE_A(td, 0, 1);
    LGKM(2); MM(1, 0, 0);
    VMC(6); BARC();
    // W8: MFMA P8(O1,n23; af1,bf1); reads P1' -> af0,bf0 (E0'); stage B(td,k0)->O0'
    RD_AF(0, 0, 0); RD_B(0, 0, 0, 0);
    STAGE_B(td, 0, 1);
    LGKM(10); MM(1, 1, 1);
    BARC();
  }

  // Tail: tile 62 in E slots (E0' staged iter-30 W3/W4; E1' staged W5/W6).
  // TW1: MFMA P1; reads P2 -> bf1; guard E1' (outstanding: 2 dummy stage-pairs = 4)
  RD_B(1, 0, 0, 1);
  LGKM(2); MM(0, 0, 0);
  VMC(4); BARC();
  // TW2: MFMA P2; reads P3 -> af1,bf0
  RD_AF(1, 0, 1); RD_B(0, 0, 1, 0);
  LGKM(10); MM(0, 1, 1);
  BARC();
  // TW3: MFMA P3; reads P4 -> bf1
  RD_B(1, 0, 1, 1);
  LGKM(2); MM(1, 0, 0);
  BARC();
  // TW4: MFMA P4
  LGKM(0); MM(1, 1, 1);
  VMC(0);  // drain dummy stages before exit

  // Epilogue: C/D layout col=lane&15, row=(lane>>4)*4+reg. out flat = cell*12288 + j'.
#pragma unroll
  for (int n = 0; n < 4; ++n) {
    int jc = n0 + wn * 64 + n * 16 + lr;
    float bv = bias[(jc % EMB) * NPATCH + (jc / EMB)];
#pragma unroll
    for (int m = 0; m < 8; ++m) {
      int row = m0 + wm * 128 + m * 16 + hi * 4;
      float* o = out + (size_t)row * N_OUT + jc;
#pragma unroll
      for (int r = 0; r < 4; ++r)
        o[(size_t)r * N_OUT] = acc[m][n][r] + bv;
    }
  }
}

// ---------------- fallback (ws too small): simple fp32 LDS-tiled GEMM, correct but slow ------
__global__ __launch_bounds__(256) void fallback_gemm(const float* __restrict__ x,
                                                     const float* __restrict__ mask,
                                                     const float* __restrict__ W,
                                                     const float* __restrict__ b,
                                                     float* __restrict__ out) {
  __shared__ float sX[64 * 33];
  __shared__ float sB2[32 * 65];
  const int t  = threadIdx.x;
  const int c0 = blockIdx.x * 64;
  const int j0 = blockIdx.y * 64;
  const int tr = t >> 4, tc = t & 15;
  float acc[4][4] = {};
  for (int k0 = 0; k0 < N_GENES; k0 += 32) {
    __syncthreads();
#pragma unroll
    for (int i = 0; i < 8; ++i) {
      int f = i * 256 + t;
      int row = f >> 5, kk = f & 31;
      sX[row * 33 + kk] = x[(size_t)(c0 + row) * N_GENES + k0 + kk];
    }
#pragma unroll
    for (int i = 0; i < 8; ++i) {
      int f = i * 256 + t;
      int kk = f >> 6, cl = f & 63;
      int jp = j0 + cl;
      int jorig = (jp % EMB) * NPATCH + jp / EMB;
      sB2[kk * 65 + cl] = W[(size_t)(k0 + kk) * N_OUT + jorig] * mask[(k0 + kk) * NPATCH + jorig / EMB];
    }
    __syncthreads();
#pragma unroll
    for (int kk = 0; kk < 32; ++kk) {
      float a[4], bb[4];
#pragma unroll
      for (int r = 0; r < 4; ++r) a[r] = sX[(tr * 4 + r) * 33 + kk];
#pragma unroll
      for (int c = 0; c < 4; ++c) bb[c] = sB2[kk * 65 + tc * 4 + c];
#pragma unroll
      for (int r = 0; r < 4; ++r)
#pragma unroll
        for (int c = 0; c < 4; ++c) acc[r][c] += a[r] * bb[c];
    }
  }
#pragma unroll
  for (int r = 0; r < 4; ++r)
#pragma unroll
    for (int c = 0; c < 4; ++c) {
      int jp = j0 + tc * 4 + c;
      int jorig = (jp % EMB) * NPATCH + jp / EMB;
      out[(size_t)(c0 + tr * 4 + r) * N_OUT + jp] = acc[r][c] + b[jorig];
    }
}

extern "C" void kernel_launch(void* const* d_in, const int* in_sizes, int n_in,
                              void* d_out, int out_size, void* d_ws, size_t ws_size,
                              hipStream_t stream) {
  const float* x    = (const float*)d_in[0];
  const float* mask = (const float*)d_in[1];
  const float* W    = (const float*)d_in[2];
  const float* b    = (const float*)d_in[3];
  float* out = (float*)d_out;

  const size_t needA = (size_t)M_CELLS * KP * sizeof(unsigned short);  // 33.0 MB
  const size_t needB = (size_t)N_OUT * KP * sizeof(unsigned short);    // 99.1 MB

  if (ws_size >= needA + needB) {
    unsigned short* Abf = (unsigned short*)d_ws;
    unsigned short* Bt  = (unsigned short*)((char*)d_ws + needA);
    prep_fused<<<4048, 256, 0, stream>>>(x, mask, W, Abf, Bt);
    gemm_bf16<<<768, 512, 0, stream>>>(Abf, Bt, b, out);
  } else {
    fallback_gemm<<<dim3(64, 192), 256, 0, stream>>>(x, mask, W, b, out);
  }
}

// Round 5
// 487.643 us; speedup vs baseline: 1.4079x; 1.4079x over previous
//
#include <hip/hip_runtime.h>
#include <hip/hip_bf16.h>

// Shapes
#define M_CELLS 4096
#define N_GENES 4000
#define KP      4032   // 63 * 64, zero-padded K
#define NKT     63     // K tiles of 64
#define N_OUT   12288  // 64 patches * 192 embed
#define EMB     192
#define NPATCH  64

#define BM 256
#define BN 256
#define BK 64
#define BTILE (BN * BK)   // 16384 elems per B K-tile

typedef __attribute__((ext_vector_type(8))) short bf16x8_t;
typedef __attribute__((ext_vector_type(8))) unsigned short u16x8_t;
typedef __attribute__((ext_vector_type(4))) float f32x4_t;

__device__ __forceinline__ unsigned short f2bf(float f) {
  __hip_bfloat16 h = __float2bfloat16(f);
  return *reinterpret_cast<unsigned short*>(&h);
}

__device__ __forceinline__ void gll16(const unsigned short* g, unsigned short* l) {
  __builtin_amdgcn_global_load_lds(
      (const __attribute__((address_space(1))) void*)g,
      (__attribute__((address_space(3))) void*)l, 16, 0, 0);
}

// ---------------- fused prep: blocks [0,1024) do prepA, [1024,4048) do prepB ----------------
__global__ __launch_bounds__(256) void prep_fused(const float* __restrict__ x,
                                                  const float* __restrict__ mask,
                                                  const float* __restrict__ W,
                                                  unsigned short* __restrict__ A,
                                                  unsigned short* __restrict__ Bt) {
  __shared__ unsigned short sT[256 * 72];  // prepB only
  const int t = threadIdx.x;
  if (blockIdx.x < 1024) {
    const int NG = M_CELLS * (KP / 8);
    for (int g = blockIdx.x * 256 + t; g < NG; g += 1024 * 256) {
      int row = g / (KP / 8);
      int kc  = g - row * (KP / 8);
      int k   = kc * 8;
      u16x8_t v;
      if (k < N_GENES) {
        float4 f0 = *reinterpret_cast<const float4*>(x + (size_t)row * N_GENES + k);
        float4 f1 = *reinterpret_cast<const float4*>(x + (size_t)row * N_GENES + k + 4);
        v[0] = f2bf(f0.x); v[1] = f2bf(f0.y); v[2] = f2bf(f0.z); v[3] = f2bf(f0.w);
        v[4] = f2bf(f1.x); v[5] = f2bf(f1.y); v[6] = f2bf(f1.z); v[7] = f2bf(f1.w);
      } else {
        v = (u16x8_t)0;
      }
      *reinterpret_cast<u16x8_t*>(A + (size_t)row * KP + k) = v;
    }
  } else {
    const int idx = blockIdx.x - 1024;
    const int jb  = idx % 48;
    const int kt  = idx / 48;
    const int j   = jb * 256 + t;
    const int pw  = j / EMB;
#pragma unroll
    for (int ch = 0; ch < 8; ++ch) {
      u16x8_t v;
#pragma unroll
      for (int u = 0; u < 8; ++u) {
        int kg = kt * 64 + ch * 8 + u;
        float val = 0.f;
        if (kg < N_GENES) val = W[(size_t)kg * N_OUT + j] * mask[kg * NPATCH + pw];
        v[u] = f2bf(val);
      }
      *reinterpret_cast<u16x8_t*>(&sT[t * 72 + ch * 8]) = v;
    }
    __syncthreads();
#pragma unroll
    for (int it = 0; it < 8; ++it) {
      int f  = it * 256 + t;
      int p  = f >> 5, u = f & 31;
      int el = u >> 3, k0 = (u & 7) * 8;
      u16x8_t v = *reinterpret_cast<const u16x8_t*>(&sT[(el * 64 + p) * 72 + k0]);
      int jp0 = p * EMB + jb * 4;
      int nt  = jp0 >> 8, c = jp0 & 255;
      *reinterpret_cast<u16x8_t*>(&Bt[(size_t)(nt * NKT + kt) * BTILE + (size_t)c * 64 + u * 8]) = v;
    }
  }
}

// ---------------- main GEMM: 256x256, BK=64, R3 schedule with balanced {8,4} phase reads -----
// Phases per slot (buf,ks): Pa = read af(m0-3)+bf(all n), MFMA acc[0..3][*];
//                           Pb = read af(m4-7),           MFMA acc[4..7][*].
// LDS slots: E0=buf0ks0, E1=buf0ks1, O0=buf1ks0, O1=buf1ks1 (16KB A + 16KB B each).
#define ABASE(buf, ks) (((buf) * 2 + (ks)) * 8192)
#define BBASE(buf, ks) (32768 + ((buf) * 2 + (ks)) * 8192)

__global__ __launch_bounds__(512, 2) void gemm_bf16(const unsigned short* __restrict__ A,
                                                    const unsigned short* __restrict__ Bt,
                                                    const float* __restrict__ bias,
                                                    float* __restrict__ out) {
  __shared__ unsigned short lds[65536];  // 128 KiB

  const int tid  = threadIdx.x;
  const int lane = tid & 63;
  const int wid  = tid >> 6;
  const int wm   = wid >> 2;   // 0..1
  const int wn   = wid & 3;    // 0..3
  const int lr   = lane & 15;
  const int hi   = lane >> 4;  // 0..3
  const int swz  = (lr >> 1) & 3;

  // XCD-chunked mapping: grid 768 = 8 XCDs x (16 mt x 6 nt_local).
  const int bid = blockIdx.x;
  const int xcd = bid & 7;
  const int l   = bid >> 3;
  const int mt  = l & 15;
  const int nt  = xcd * 6 + (l >> 4);
  const int m0  = mt * BM;
  const int n0  = nt * BN;

  // fragment LDS element offsets (within a [256][32] chunk), swizzle slot^((row>>1)&3)
  const int aoff = (wm * 128 + lr) * 32 + ((hi ^ swz) << 3);
  const int boff = (wn * 64 + lr) * 32 + ((hi ^ swz) << 3);

  // staging source base pointers (per-thread); LDS dest linear tid*16B
  const int srow = tid >> 2;
  const int ssl  = ((tid & 3) ^ ((tid >> 3) & 3)) << 3;  // inverse-swizzled 16B slot
  const unsigned short* aS0 = A + (size_t)(m0 + srow) * KP + ssl;
  const unsigned short* aS1 = aS0 + (size_t)128 * KP;
  const unsigned short* bS0 = Bt + (size_t)nt * NKT * BTILE + (size_t)srow * 64 + ssl;
  const unsigned short* bS1 = bS0 + 8192;

#define STAGE_A(kt, kh, buf) { \
    gll16(aS0 + (kt) * 64 + (kh) * 32, &lds[ABASE(buf, kh) + tid * 8]); \
    gll16(aS1 + (kt) * 64 + (kh) * 32, &lds[ABASE(buf, kh) + 4096 + tid * 8]); }
#define STAGE_B(kt, kh, buf) { \
    gll16(bS0 + (size_t)(kt) * BTILE + (kh) * 32, &lds[BBASE(buf, kh) + tid * 8]); \
    gll16(bS1 + (size_t)(kt) * BTILE + (kh) * 32, &lds[BBASE(buf, kh) + 4096 + tid * 8]); }

// read A-frag half mh (4 regs), all-4 B frags
#define RD_A4(buf, ks, mh) \
    _Pragma("unroll") for (int m_ = 0; m_ < 4; ++m_) \
      af[m_] = *reinterpret_cast<const bf16x8_t*>(&lds[ABASE(buf, ks) + aoff + ((mh) * 4 + m_) * 512]);
#define RD_B4(buf, ks) \
    _Pragma("unroll") for (int n_ = 0; n_ < 4; ++n_) \
      bfr[n_] = *reinterpret_cast<const bf16x8_t*>(&lds[BBASE(buf, ks) + boff + n_ * 512]);

#define MM16(mh) \
    __builtin_amdgcn_s_setprio(1); \
    _Pragma("unroll") for (int m_ = 0; m_ < 4; ++m_) \
    _Pragma("unroll") for (int n_ = 0; n_ < 4; ++n_) \
      acc[(mh) * 4 + m_][n_] = __builtin_amdgcn_mfma_f32_16x16x32_bf16( \
          af[m_], bfr[n_], acc[(mh) * 4 + m_][n_], 0, 0, 0); \
    __builtin_amdgcn_s_setprio(0);

#define PH_OPEN() \
    __builtin_amdgcn_s_barrier(); \
    asm volatile("s_waitcnt lgkmcnt(0)" ::: "memory"); \
    __builtin_amdgcn_sched_barrier(0);
#define PH_CLOSE() \
    __builtin_amdgcn_s_barrier(); \
    __builtin_amdgcn_sched_barrier(0);
#define PH_CLOSE_VM(N) \
    asm volatile("s_waitcnt vmcnt(" #N ")" ::: "memory"); \
    __builtin_amdgcn_s_barrier(); \
    __builtin_amdgcn_sched_barrier(0);

  f32x4_t acc[8][4] = {};
  bf16x8_t af[4], bfr[4];

  // Prologue: stage E0, E1, O0 (12 loads); vmcnt(4) -> E0+E1 done.
  STAGE_A(0, 0, 0); STAGE_B(0, 0, 0);
  STAGE_A(0, 1, 0); STAGE_B(0, 1, 0);
  STAGE_A(1, 0, 1); STAGE_B(1, 0, 1);
  asm volatile("s_waitcnt vmcnt(4)" ::: "memory");
  __builtin_amdgcn_s_barrier();
  __builtin_amdgcn_sched_barrier(0);

  for (int i = 0; i < 31; ++i) {
    const int tb = 2 * i + 1, tc = 2 * i + 2;
    const int td = (tb + 2 <= 62) ? tb + 2 : 62;  // clamped dummy stage on last iter

    // W1: Pa(E0); stage A(tb,k1)->O1; close guards E1 (first read W3)
    RD_A4(0, 0, 0); RD_B4(0, 0);
    STAGE_A(tb, 1, 1);
    PH_OPEN(); MM16(0); PH_CLOSE_VM(6);
    // W2: Pb(E0); stage B(tb,k1)->O1
    RD_A4(0, 0, 1);
    STAGE_B(tb, 1, 1);
    PH_OPEN(); MM16(1); PH_CLOSE();
    // W3: Pa(E1); stage A(tc,k0)->E0'; close guards O0 (first read W5)
    RD_A4(0, 1, 0); RD_B4(0, 1);
    STAGE_A(tc, 0, 0);
    PH_OPEN(); MM16(0); PH_CLOSE_VM(6);
    // W4: Pb(E1); stage B(tc,k0)->E0'
    RD_A4(0, 1, 1);
    STAGE_B(tc, 0, 0);
    PH_OPEN(); MM16(1); PH_CLOSE();
    // W5: Pa(O0); stage A(tc,k1)->E1'; close guards O1 (first read W7)
    RD_A4(1, 0, 0); RD_B4(1, 0);
    STAGE_A(tc, 1, 0);
    PH_OPEN(); MM16(0); PH_CLOSE_VM(6);
    // W6: Pb(O0); stage B(tc,k1)->E1'
    RD_A4(1, 0, 1);
    STAGE_B(tc, 1, 0);
    PH_OPEN(); MM16(1); PH_CLOSE();
    // W7: Pa(O1); stage A(td,k0)->O0'; close guards E0' (first read next-iter W1)
    RD_A4(1, 1, 0); RD_B4(1, 1);
    STAGE_A(td, 0, 1);
    PH_OPEN(); MM16(0); PH_CLOSE_VM(6);
    // W8: Pb(O1); stage B(td,k0)->O0'
    RD_A4(1, 1, 1);
    STAGE_B(td, 0, 1);
    PH_OPEN(); MM16(1); PH_CLOSE();
  }

  // Tail: tile 62 in E slots (E0 staged i30 W3/W4 [landed by W7's vmcnt]; E1 staged W5/W6).
  RD_A4(0, 0, 0); RD_B4(0, 0);
  PH_OPEN(); MM16(0); PH_CLOSE_VM(4);   // guards E1 (4 newest = W7/W8 dummies)
  RD_A4(0, 0, 1);
  PH_OPEN(); MM16(1); PH_CLOSE();
  RD_A4(0, 1, 0); RD_B4(0, 1);
  PH_OPEN(); MM16(0); PH_CLOSE();
  RD_A4(0, 1, 1);
  PH_OPEN(); MM16(1);
  asm volatile("s_waitcnt vmcnt(0)" ::: "memory");  // drain dummy stages
  __builtin_amdgcn_s_barrier();

  // Epilogue: C/D layout col=lane&15, row=(lane>>4)*4+reg. out flat = cell*12288 + j'.
#pragma unroll
  for (int n = 0; n < 4; ++n) {
    int jc = n0 + wn * 64 + n * 16 + lr;
    float bv = bias[(jc % EMB) * NPATCH + (jc / EMB)];
#pragma unroll
    for (int m = 0; m < 8; ++m) {
      int row = m0 + wm * 128 + m * 16 + hi * 4;
      float* o = out + (size_t)row * N_OUT + jc;
#pragma unroll
      for (int r = 0; r < 4; ++r)
        o[(size_t)r * N_OUT] = acc[m][n][r] + bv;
    }
  }
}

// ---------------- fallback (ws too small): simple fp32 LDS-tiled GEMM, correct but slow ------
__global__ __launch_bounds__(256) void fallback_gemm(const float* __restrict__ x,
                                                     const float* __restrict__ mask,
                                                     const float* __restrict__ W,
                                                     const float* __restrict__ b,
                                                     float* __restrict__ out) {
  __shared__ float sX[64 * 33];
  __shared__ float sB2[32 * 65];
  const int t  = threadIdx.x;
  const int c0 = blockIdx.x * 64;
  const int j0 = blockIdx.y * 64;
  const int tr = t >> 4, tc = t & 15;
  float acc[4][4] = {};
  for (int k0 = 0; k0 < N_GENES; k0 += 32) {
    __syncthreads();
#pragma unroll
    for (int i = 0; i < 8; ++i) {
      int f = i * 256 + t;
      int row = f >> 5, kk = f & 31;
      sX[row * 33 + kk] = x[(size_t)(c0 + row) * N_GENES + k0 + kk];
    }
#pragma unroll
    for (int i = 0; i < 8; ++i) {
      int f = i * 256 + t;
      int kk = f >> 6, cl = f & 63;
      int jp = j0 + cl;
      int jorig = (jp % EMB) * NPATCH + jp / EMB;
      sB2[kk * 65 + cl] = W[(size_t)(k0 + kk) * N_OUT + jorig] * mask[(k0 + kk) * NPATCH + jorig / EMB];
    }
    __syncthreads();
#pragma unroll
    for (int kk = 0; kk < 32; ++kk) {
      float a[4], bb[4];
#pragma unroll
      for (int r = 0; r < 4; ++r) a[r] = sX[(tr * 4 + r) * 33 + kk];
#pragma unroll
      for (int c = 0; c < 4; ++c) bb[c] = sB2[kk * 65 + tc * 4 + c];
#pragma unroll
      for (int r = 0; r < 4; ++r)
#pragma unroll
        for (int c = 0; c < 4; ++c) acc[r][c] += a[r] * bb[c];
    }
  }
#pragma unroll
  for (int r = 0; r < 4; ++r)
#pragma unroll
    for (int c = 0; c < 4; ++c) {
      int jp = j0 + tc * 4 + c;
      int jorig = (jp % EMB) * NPATCH + jp / EMB;
      out[(size_t)(c0 + tr * 4 + r) * N_OUT + jp] = acc[r][c] + b[jorig];
    }
}

extern "C" void kernel_launch(void* const* d_in, const int* in_sizes, int n_in,
                              void* d_out, int out_size, void* d_ws, size_t ws_size,
                              hipStream_t stream) {
  const float* x    = (const float*)d_in[0];
  const float* mask = (const float*)d_in[1];
  const float* W    = (const float*)d_in[2];
  const float* b    = (const float*)d_in[3];
  float* out = (float*)d_out;

  const size_t needA = (size_t)M_CELLS * KP * sizeof(unsigned short);  // 33.0 MB
  const size_t needB = (size_t)N_OUT * KP * sizeof(unsigned short);    // 99.1 MB

  if (ws_size >= needA + needB) {
    unsigned short* Abf = (unsigned short*)d_ws;
    unsigned short* Bt  = (unsigned short*)((char*)d_ws + needA);
    prep_fused<<<4048, 256, 0, stream>>>(x, mask, W, Abf, Bt);
    gemm_bf16<<<768, 512, 0, stream>>>(Abf, Bt, b, out);
  } else {
    fallback_gemm<<<dim3(64, 192), 256, 0, stream>>>(x, mask, W, b, out);
  }
}

// Round 6
// 482.943 us; speedup vs baseline: 1.4216x; 1.0097x over previous
//
#include <hip/hip_runtime.h>
#include <hip/hip_bf16.h>

// Shapes
#define M_CELLS 4096
#define N_GENES 4000
#define KP      4032   // 63 * 64, zero-padded K
#define NKT     63     // K tiles of 64
#define N_OUT   12288  // 64 patches * 192 embed
#define EMB     192
#define NPATCH  64

#define BM 256
#define BN 256
#define BK 64
#define BTILE (BN * BK)   // 16384 elems per B K-tile

typedef __attribute__((ext_vector_type(8))) short bf16x8_t;
typedef __attribute__((ext_vector_type(8))) unsigned short u16x8_t;
typedef __attribute__((ext_vector_type(4))) float f32x4_t;

__device__ __forceinline__ unsigned short f2bf(float f) {
  __hip_bfloat16 h = __float2bfloat16(f);
  return *reinterpret_cast<unsigned short*>(&h);
}

__device__ __forceinline__ void gll16(const unsigned short* g, unsigned short* l) {
  __builtin_amdgcn_global_load_lds(
      (const __attribute__((address_space(1))) void*)g,
      (__attribute__((address_space(3))) void*)l, 16, 0, 0);
}

// ---------------- fused prep: blocks [0,1024) do prepA, [1024,4048) do prepB ----------------
// prepB sT: [256 rows][64 elems] (128 B rows), chunk XOR-swizzled: slot = ch ^ (row&7).
// Conflict-free b128 on both write and read (8-lane groups cover all 32 banks).
__global__ __launch_bounds__(256) void prep_fused(const float* __restrict__ x,
                                                  const float* __restrict__ mask,
                                                  const float* __restrict__ W,
                                                  unsigned short* __restrict__ A,
                                                  unsigned short* __restrict__ Bt) {
  __shared__ unsigned short sT[256 * 64];  // prepB only
  const int t = threadIdx.x;
  if (blockIdx.x < 1024) {
    const int NG = M_CELLS * (KP / 8);
    for (int g = blockIdx.x * 256 + t; g < NG; g += 1024 * 256) {
      int row = g / (KP / 8);
      int kc  = g - row * (KP / 8);
      int k   = kc * 8;
      u16x8_t v;
      if (k < N_GENES) {
        float4 f0 = *reinterpret_cast<const float4*>(x + (size_t)row * N_GENES + k);
        float4 f1 = *reinterpret_cast<const float4*>(x + (size_t)row * N_GENES + k + 4);
        v[0] = f2bf(f0.x); v[1] = f2bf(f0.y); v[2] = f2bf(f0.z); v[3] = f2bf(f0.w);
        v[4] = f2bf(f1.x); v[5] = f2bf(f1.y); v[6] = f2bf(f1.z); v[7] = f2bf(f1.w);
      } else {
        v = (u16x8_t)0;
      }
      *reinterpret_cast<u16x8_t*>(A + (size_t)row * KP + k) = v;
    }
  } else {
    const int idx = blockIdx.x - 1024;
    const int jb  = idx % 48;
    const int kt  = idx / 48;
    const int j   = jb * 256 + t;
    const int pw  = j / EMB;
#pragma unroll
    for (int ch = 0; ch < 8; ++ch) {
      u16x8_t v;
#pragma unroll
      for (int u = 0; u < 8; ++u) {
        int kg = kt * 64 + ch * 8 + u;
        float val = 0.f;
        if (kg < N_GENES) val = W[(size_t)kg * N_OUT + j] * mask[kg * NPATCH + pw];
        v[u] = f2bf(val);
      }
      *reinterpret_cast<u16x8_t*>(&sT[t * 64 + ((ch ^ (t & 7)) * 8)]) = v;
    }
    __syncthreads();
#pragma unroll
    for (int it = 0; it < 8; ++it) {
      int f  = it * 256 + t;
      int p  = f >> 5, u = f & 31;
      int el = u >> 3;
      int r  = el * 64 + p;                      // source row in sT
      u16x8_t v = *reinterpret_cast<const u16x8_t*>(&sT[r * 64 + (((u & 7) ^ (r & 7)) * 8)]);
      int jp0 = p * EMB + jb * 4;
      int nt  = jp0 >> 8, c = jp0 & 255;
      *reinterpret_cast<u16x8_t*>(&Bt[(size_t)(nt * NKT + kt) * BTILE + (size_t)c * 64 + u * 8]) = v;
    }
  }
}

// ---------------- main GEMM: 256x256, BK=64, R5 window ring, compiler-scheduled lgkm --------
// Change vs R5: no hard lgkmcnt(0) drain; raw s_barrier + zero-cost compiler fences pin
// memory-op motion, compiler emits counted lgkmcnt per MFMA use -> ds_read drain overlaps
// the MFMA cluster. vmcnt(N) publish guards (hardware) unchanged.
#define ABASE(buf, ks) (((buf) * 2 + (ks)) * 8192)
#define BBASE(buf, ks) (32768 + ((buf) * 2 + (ks)) * 8192)

__global__ __launch_bounds__(512, 2) void gemm_bf16(const unsigned short* __restrict__ A,
                                                    const unsigned short* __restrict__ Bt,
                                                    const float* __restrict__ bias,
                                                    float* __restrict__ out) {
  __shared__ unsigned short lds[65536];  // 128 KiB

  const int tid  = threadIdx.x;
  const int lane = tid & 63;
  const int wid  = tid >> 6;
  const int wm   = wid >> 2;   // 0..1
  const int wn   = wid & 3;    // 0..3
  const int lr   = lane & 15;
  const int hi   = lane >> 4;  // 0..3
  const int swz  = (lr >> 1) & 3;

  // XCD-chunked mapping: grid 768 = 8 XCDs x (16 mt x 6 nt_local).
  const int bid = blockIdx.x;
  const int xcd = bid & 7;
  const int l   = bid >> 3;
  const int mt  = l & 15;
  const int nt  = xcd * 6 + (l >> 4);
  const int m0  = mt * BM;
  const int n0  = nt * BN;

  // fragment LDS element offsets (within a [256][32] chunk), swizzle slot^((row>>1)&3)
  const int aoff = (wm * 128 + lr) * 32 + ((hi ^ swz) << 3);
  const int boff = (wn * 64 + lr) * 32 + ((hi ^ swz) << 3);

  // staging source base pointers (per-thread); LDS dest linear tid*16B
  const int srow = tid >> 2;
  const int ssl  = ((tid & 3) ^ ((tid >> 3) & 3)) << 3;  // inverse-swizzled 16B slot
  const unsigned short* aS0 = A + (size_t)(m0 + srow) * KP + ssl;
  const unsigned short* aS1 = aS0 + (size_t)128 * KP;
  const unsigned short* bS0 = Bt + (size_t)nt * NKT * BTILE + (size_t)srow * 64 + ssl;
  const unsigned short* bS1 = bS0 + 8192;

#define STAGE_A(kt, kh, buf) { \
    gll16(aS0 + (kt) * 64 + (kh) * 32, &lds[ABASE(buf, kh) + tid * 8]); \
    gll16(aS1 + (kt) * 64 + (kh) * 32, &lds[ABASE(buf, kh) + 4096 + tid * 8]); }
#define STAGE_B(kt, kh, buf) { \
    gll16(bS0 + (size_t)(kt) * BTILE + (kh) * 32, &lds[BBASE(buf, kh) + tid * 8]); \
    gll16(bS1 + (size_t)(kt) * BTILE + (kh) * 32, &lds[BBASE(buf, kh) + 4096 + tid * 8]); }

// Pa read set, ordered for earliest first-MFMA: af0, bf0..3, af1..3
#define RD_PA(buf, ks) { \
    af[0] = *reinterpret_cast<const bf16x8_t*>(&lds[ABASE(buf, ks) + aoff]); \
    _Pragma("unroll") for (int n_ = 0; n_ < 4; ++n_) \
      bfr[n_] = *reinterpret_cast<const bf16x8_t*>(&lds[BBASE(buf, ks) + boff + n_ * 512]); \
    _Pragma("unroll") for (int m_ = 1; m_ < 4; ++m_) \
      af[m_] = *reinterpret_cast<const bf16x8_t*>(&lds[ABASE(buf, ks) + aoff + m_ * 512]); }
// Pb read set: af(m4-7)
#define RD_PB(buf, ks) \
    _Pragma("unroll") for (int m_ = 0; m_ < 4; ++m_) \
      af[m_] = *reinterpret_cast<const bf16x8_t*>(&lds[ABASE(buf, ks) + aoff + (4 + m_) * 512]);

#define MM16(mh) \
    __builtin_amdgcn_s_setprio(1); \
    _Pragma("unroll") for (int m_ = 0; m_ < 4; ++m_) \
    _Pragma("unroll") for (int n_ = 0; n_ < 4; ++n_) \
      acc[(mh) * 4 + m_][n_] = __builtin_amdgcn_mfma_f32_16x16x32_bf16( \
          af[m_], bfr[n_], acc[(mh) * 4 + m_][n_], 0, 0, 0); \
    __builtin_amdgcn_s_setprio(0);

#define SFENCE() asm volatile("" ::: "memory")
#define PH_OPEN() \
    SFENCE(); __builtin_amdgcn_s_barrier(); SFENCE();
#define PH_CLOSE() \
    SFENCE(); __builtin_amdgcn_s_barrier(); SFENCE();
#define PH_CLOSE_VM(N) \
    asm volatile("s_waitcnt vmcnt(" #N ")" ::: "memory"); \
    __builtin_amdgcn_s_barrier(); SFENCE();

  f32x4_t acc[8][4] = {};
  bf16x8_t af[4], bfr[4];

  // Prologue: stage E0, E1, O0 (12 loads); vmcnt(4) -> E0+E1 done.
  STAGE_A(0, 0, 0); STAGE_B(0, 0, 0);
  STAGE_A(0, 1, 0); STAGE_B(0, 1, 0);
  STAGE_A(1, 0, 1); STAGE_B(1, 0, 1);
  asm volatile("s_waitcnt vmcnt(4)" ::: "memory");
  __builtin_amdgcn_s_barrier();
  SFENCE();

  for (int i = 0; i < 31; ++i) {
    const int tb = 2 * i + 1, tc = 2 * i + 2;
    const int td = (tb + 2 <= 62) ? tb + 2 : 62;  // clamped dummy stage on last iter

    // W1: Pa(E0); stage A(tb,k1)->O1; close guards E1 (first read W3)
    RD_PA(0, 0);
    STAGE_A(tb, 1, 1);
    PH_OPEN(); MM16(0); PH_CLOSE_VM(6);
    // W2: Pb(E0); stage B(tb,k1)->O1
    RD_PB(0, 0);
    STAGE_B(tb, 1, 1);
    PH_OPEN(); MM16(1); PH_CLOSE();
    // W3: Pa(E1); stage A(tc,k0)->E0'; close guards O0 (first read W5)
    RD_PA(0, 1);
    STAGE_A(tc, 0, 0);
    PH_OPEN(); MM16(0); PH_CLOSE_VM(6);
    // W4: Pb(E1); stage B(tc,k0)->E0'
    RD_PB(0, 1);
    STAGE_B(tc, 0, 0);
    PH_OPEN(); MM16(1); PH_CLOSE();
    // W5: Pa(O0); stage A(tc,k1)->E1'; close guards O1 (first read W7)
    RD_PA(1, 0);
    STAGE_A(tc, 1, 0);
    PH_OPEN(); MM16(0); PH_CLOSE_VM(6);
    // W6: Pb(O0); stage B(tc,k1)->E1'
    RD_PB(1, 0);
    STAGE_B(tc, 1, 0);
    PH_OPEN(); MM16(1); PH_CLOSE();
    // W7: Pa(O1); stage A(td,k0)->O0'; close guards E0' (first read next-iter W1)
    RD_PA(1, 1);
    STAGE_A(td, 0, 1);
    PH_OPEN(); MM16(0); PH_CLOSE_VM(6);
    // W8: Pb(O1); stage B(td,k0)->O0'
    RD_PB(1, 1);
    STAGE_B(td, 0, 1);
    PH_OPEN(); MM16(1); PH_CLOSE();
  }

  // Tail: tile 62 in E slots (E0 staged i30 W3/W4 [landed by W7's vmcnt]; E1 staged W5/W6).
  RD_PA(0, 0);
  PH_OPEN(); MM16(0); PH_CLOSE_VM(4);   // guards E1 (4 newest = W7/W8 dummies)
  RD_PB(0, 0);
  PH_OPEN(); MM16(1); PH_CLOSE();
  RD_PA(0, 1);
  PH_OPEN(); MM16(0); PH_CLOSE();
  RD_PB(0, 1);
  PH_OPEN(); MM16(1);
  asm volatile("s_waitcnt vmcnt(0)" ::: "memory");  // drain dummy stages
  __builtin_amdgcn_s_barrier();

  // Epilogue: C/D layout col=lane&15, row=(lane>>4)*4+reg. out flat = cell*12288 + j'.
#pragma unroll
  for (int n = 0; n < 4; ++n) {
    int jc = n0 + wn * 64 + n * 16 + lr;
    float bv = bias[(jc % EMB) * NPATCH + (jc / EMB)];
#pragma unroll
    for (int m = 0; m < 8; ++m) {
      int row = m0 + wm * 128 + m * 16 + hi * 4;
      float* o = out + (size_t)row * N_OUT + jc;
#pragma unroll
      for (int r = 0; r < 4; ++r)
        o[(size_t)r * N_OUT] = acc[m][n][r] + bv;
    }
  }
}

// ---------------- fallback (ws too small): simple fp32 LDS-tiled GEMM, correct but slow ------
__global__ __launch_bounds__(256) void fallback_gemm(const float* __restrict__ x,
                                                     const float* __restrict__ mask,
                                                     const float* __restrict__ W,
                                                     const float* __restrict__ b,
                                                     float* __restrict__ out) {
  __shared__ float sX[64 * 33];
  __shared__ float sB2[32 * 65];
  const int t  = threadIdx.x;
  const int c0 = blockIdx.x * 64;
  const int j0 = blockIdx.y * 64;
  const int tr = t >> 4, tc = t & 15;
  float acc[4][4] = {};
  for (int k0 = 0; k0 < N_GENES; k0 += 32) {
    __syncthreads();
#pragma unroll
    for (int i = 0; i < 8; ++i) {
      int f = i * 256 + t;
      int row = f >> 5, kk = f & 31;
      sX[row * 33 + kk] = x[(size_t)(c0 + row) * N_GENES + k0 + kk];
    }
#pragma unroll
    for (int i = 0; i < 8; ++i) {
      int f = i * 256 + t;
      int kk = f >> 6, cl = f & 63;
      int jp = j0 + cl;
      int jorig = (jp % EMB) * NPATCH + jp / EMB;
      sB2[kk * 65 + cl] = W[(size_t)(k0 + kk) * N_OUT + jorig] * mask[(k0 + kk) * NPATCH + jorig / EMB];
    }
    __syncthreads();
#pragma unroll
    for (int kk = 0; kk < 32; ++kk) {
      float a[4], bb[4];
#pragma unroll
      for (int r = 0; r < 4; ++r) a[r] = sX[(tr * 4 + r) * 33 + kk];
#pragma unroll
      for (int c = 0; c < 4; ++c) bb[c] = sB2[kk * 65 + tc * 4 + c];
#pragma unroll
      for (int r = 0; r < 4; ++r)
#pragma unroll
        for (int c = 0; c < 4; ++c) acc[r][c] += a[r] * bb[c];
    }
  }
#pragma unroll
  for (int r = 0; r < 4; ++r)
#pragma unroll
    for (int c = 0; c < 4; ++c) {
      int jp = j0 + tc * 4 + c;
      int jorig = (jp % EMB) * NPATCH + jp / EMB;
      out[(size_t)(c0 + tr * 4 + r) * N_OUT + jp] = acc[r][c] + b[jorig];
    }
}

extern "C" void kernel_launch(void* const* d_in, const int* in_sizes, int n_in,
                              void* d_out, int out_size, void* d_ws, size_t ws_size,
                              hipStream_t stream) {
  const float* x    = (const float*)d_in[0];
  const float* mask = (const float*)d_in[1];
  const float* W    = (const float*)d_in[2];
  const float* b    = (const float*)d_in[3];
  float* out = (float*)d_out;

  const size_t needA = (size_t)M_CELLS * KP * sizeof(unsigned short);  // 33.0 MB
  const size_t needB = (size_t)N_OUT * KP * sizeof(unsigned short);    // 99.1 MB

  if (ws_size >= needA + needB) {
    unsigned short* Abf = (unsigned short*)d_ws;
    unsigned short* Bt  = (unsigned short*)((char*)d_ws + needA);
    prep_fused<<<4048, 256, 0, stream>>>(x, mask, W, Abf, Bt);
    gemm_bf16<<<768, 512, 0, stream>>>(Abf, Bt, b, out);
  } else {
    fallback_gemm<<<dim3(64, 192), 256, 0, stream>>>(x, mask, W, b, out);
  }
}